// Round 4
// baseline (376.822 us; speedup 1.0000x reference)
//
#include <hip/hip_runtime.h>
#include <hip/hip_bf16.h>

#define NB 256
#define NR 100
#define ND 6168
#define DP 6272            // padded to multiple of 128
#define NH 128
#define NC 100
#define CP 112             // NC padded to multiple of 16
#define KSTEP 32
#define NG (DP / 128)      // 49 groups of K=128
#define NT (DP / KSTEP)    // 196 tiles of K=32

typedef __attribute__((ext_vector_type(8))) __bf16 bf16x8;
typedef __attribute__((ext_vector_type(4))) float f32x4;
typedef __attribute__((ext_vector_type(4))) int i32x4;
typedef __attribute__((ext_vector_type(4))) unsigned int u32x4;

// Non-draining barrier (T4): LDS ordering only; vmem stays in flight.
// NO "memory" clobber (it would force conservative vmcnt drain); order is
// pinned by sched_barrier(0) instead (guide rule #18 / m201 template).
#define BAR() do { \
  __builtin_amdgcn_sched_barrier(0); \
  asm volatile("s_waitcnt lgkmcnt(0)"); \
  __builtin_amdgcn_sched_barrier(0); \
  __builtin_amdgcn_s_barrier(); \
  __builtin_amdgcn_sched_barrier(0); \
} while (0)

// ---------- prep 1: W1 (ND,NH) f32 -> W1T (NH, DP) bf16, zero-padded ----------
__global__ void prep_w1t(const float* __restrict__ W1, __hip_bfloat16* __restrict__ W1T) {
  __shared__ float tile[KSTEP][NH + 1];
  const int d0 = blockIdx.x * KSTEP;
  const int t = threadIdx.x;
#pragma unroll
  for (int p = 0; p < (KSTEP * NH) / 256; ++p) {
    int idx = p * 256 + t;
    int dd = idx >> 7;
    int h  = idx & 127;
    int d  = d0 + dd;
    tile[dd][h] = (d < ND) ? W1[d * NH + h] : 0.f;
  }
  __syncthreads();
#pragma unroll
  for (int p = 0; p < (KSTEP * NH) / 256; ++p) {
    int idx = p * 256 + t;
    int h  = idx >> 5;
    int dd = idx & 31;
    W1T[h * DP + d0 + dd] = __float2bfloat16(tile[dd][h]);
  }
}

// ---------- prep 2: W2 (NH,NC) f32 -> W2T (CP, NH) bf16, zero rows for c>=NC ----------
__global__ void prep_w2t(const float* __restrict__ W2, __hip_bfloat16* __restrict__ W2T) {
  int t = blockIdx.x * 256 + threadIdx.x;
  if (t < CP * NH) {
    int c = t >> 7;
    int h = t & 127;
    float v = (c < NC) ? W2[h * NC + c] : 0.f;
    W2T[t] = __float2bfloat16(v);
  }
}

// ---------- main fused kernel: one block per b, 256 threads (4 waves) ----------
// LDS (bytes):
//   [0, 12544)      xpair: 3136 dwords, (x[2i]&1) | (x[2i+1]&1)<<16
//   [12544, 33024)  BF0: A [128 x 80B] then B [128 x 80B]
//   [33024, 53504)  BF1
//   epilogue overlay at 0: h_tile [128][136] bf16 (34816 B); partial [8][112] f32 at 34816
__launch_bounds__(256, 1)
__global__ void fused_main(const int* __restrict__ x,
                           const int* __restrict__ noise,
                           const __hip_bfloat16* __restrict__ W1T,
                           const float* __restrict__ b1,
                           const __hip_bfloat16* __restrict__ W2T,
                           const float* __restrict__ b2,
                           float* __restrict__ out) {
  __shared__ __align__(16) char lds[53504];
  unsigned int* xpair = (unsigned int*)lds;
  char* const BF0 = lds + 12544;
  char* const BF1 = BF0 + 20480;

  const int tid  = threadIdx.x;
  const int lane = tid & 63;
  const int w    = tid >> 6;       // wave 0..3
  const int lq   = lane >> 4;
  const int lm   = lane & 15;
  const int b    = blockIdx.x;

  const int r  = tid >> 1;         // staging row 0..127
  const int kh = tid & 1;          // 64-int half within a 128-int group
  const bool rvalid = (r < NR);

  const int*  nrow  = noise + (long)b * NR * ND + (long)r * ND;   // row base (ints)
  const char* wrow  = (const char*)W1T + (long)r * DP * 2 + (kh ^ 1) * 128;

  f32x4 acc[8][2] = {};
  i32x4 nA[16], nB[16], wA[8], wB[8];

  // ---- load a group's noise: 256B contiguous per thread (16 burst loads) ----
  auto ISSUE_N = [&](int g, i32x4* n) {
    i32x4 z = {0, 0, 0, 0};
    const int base = g * 128 + kh * 64;
#pragma unroll
    for (int j = 0; j < 16; ++j) {
      int k0 = base + j * 4;
      n[j] = (rvalid && k0 + 4 <= ND) ? *(const i32x4*)(nrow + base + j * 4) : z;
    }
  };
  // ---- load a group's W1T slice: 128B contiguous per thread (8 burst loads) ----
  auto ISSUE_W = [&](int g, i32x4* wv) {
    const char* src = wrow + g * 256;
#pragma unroll
    for (int j = 0; j < 8; ++j) wv[j] = *(const i32x4*)(src + j * 16);
  };

  // ---- stage tile p (0..3) of group g into LDS buffer ----
  auto STORE_T = [&](const i32x4* n, const i32x4* wv, int g, int p, char* buf) {
    if (kh == (p >> 1)) {
      // this thread holds the full 32-int noise row chunk for tile p
      const int rb = (p & 1) * 8;
      u32x4 xp[4];
#pragma unroll
      for (int c = 0; c < 4; ++c) xp[c] = *(const u32x4*)(xpair + g * 64 + p * 16 + c * 4);
      unsigned pk[16];
#pragma unroll
      for (int q = 0; q < 16; ++q) {
        unsigned n0 = (unsigned)n[rb + (q >> 1)][(q & 1) * 2];
        unsigned n1 = (unsigned)n[rb + (q >> 1)][(q & 1) * 2 + 1];
        pk[q] = ((n0 | (n1 << 16)) ^ xp[q >> 2][q & 3]) * 0x3F80u;
      }
#pragma unroll
      for (int c = 0; c < 4; ++c) {
        u32x4 t = {pk[c * 4], pk[c * 4 + 1], pk[c * 4 + 2], pk[c * 4 + 3]};
        *(u32x4*)(buf + r * 80 + c * 16) = t;
      }
    } else {
      // this thread holds the full 64B W1T row chunk for tile p
      const int rb = (p & 1) * 4;
#pragma unroll
      for (int c = 0; c < 4; ++c)
        *(i32x4*)(buf + 10240 + r * 80 + c * 16) = wv[rb + c];
    }
  };

  auto COMPUTE = [&](const char* buf) {
    const char* Bb = buf + 10240;
    bf16x8 bf0 = *(const bf16x8*)(Bb + (w * 32 + lm) * 80 + lq * 16);
    bf16x8 bf1 = *(const bf16x8*)(Bb + (w * 32 + 16 + lm) * 80 + lq * 16);
#pragma unroll
    for (int mf = 0; mf < 8; ++mf) {
      bf16x8 af = *(const bf16x8*)(buf + (mf * 16 + lm) * 80 + lq * 16);
      acc[mf][0] = __builtin_amdgcn_mfma_f32_16x16x32_bf16(af, bf0, acc[mf][0], 0, 0, 0);
      acc[mf][1] = __builtin_amdgcn_mfma_f32_16x16x32_bf16(af, bf1, acc[mf][1], 0, 0, 0);
    }
  };

  // ---- prologue ----
  ISSUE_N(0, nA); ISSUE_W(0, wA);
  ISSUE_N(1, nB); ISSUE_W(1, wB);
  {
    const int* xb = x + b * ND;
    for (int i = tid; i < DP / 2; i += 256) {
      unsigned p = 0;
      if (2 * i + 1 < ND) {
        int2 v = *(const int2*)(xb + 2 * i);
        p = ((unsigned)v.x & 1u) | (((unsigned)v.y & 1u) << 16);
      }
      xpair[i] = p;
    }
  }
  BAR();
  STORE_T(nA, wA, 0, 0, BF0);     // tile 0
  BAR();

  // ---- main loop: 4-phase groups, 2 group-slots, burst reissue at p2 ----
#define GROUP_BODY(g, curN, curW, nxtN, nxtW)                         \
  do {                                                                \
    COMPUTE(BF0);                       /* tile 4g   */               \
    STORE_T(curN, curW, (g), 1, BF1);   /* tile 4g+1 */               \
    BAR();                                                            \
    COMPUTE(BF1);                       /* tile 4g+1 */               \
    STORE_T(curN, curW, (g), 2, BF0);   /* tile 4g+2 */               \
    BAR();                                                            \
    COMPUTE(BF0);                       /* tile 4g+2 */               \
    STORE_T(curN, curW, (g), 3, BF1);   /* tile 4g+3 */               \
    if ((g) + 2 < NG) { ISSUE_N((g) + 2, curN); ISSUE_W((g) + 2, curW); } \
    BAR();                                                            \
    COMPUTE(BF1);                       /* tile 4g+3 */               \
    if (4 * (g) + 4 < NT) STORE_T(nxtN, nxtW, (g) + 1, 0, BF0);       \
    BAR();                                                            \
  } while (0)

  for (int gg = 0; gg < NG; gg += 2) {
    GROUP_BODY(gg, nA, wA, nB, wB);
    if (gg + 1 < NG) GROUP_BODY(gg + 1, nB, wB, nA, wA);
  }
#undef GROUP_BODY

  // ---------------- epilogue ----------------
  __syncthreads();
  __hip_bfloat16* h_tile = (__hip_bfloat16*)lds;        // [128][136]
  float* partial = (float*)(lds + 34816);                // [8][112]

#pragma unroll
  for (int nf = 0; nf < 2; ++nf) {
    int hcol = w * 32 + nf * 16 + lm;
    float bb = b1[hcol];
#pragma unroll
    for (int mf = 0; mf < 8; ++mf) {
#pragma unroll
      for (int rg = 0; rg < 4; ++rg) {
        int m = mf * 16 + lq * 4 + rg;
        h_tile[m * 136 + hcol] = __float2bfloat16(tanhf(acc[mf][nf][rg] + bb));
      }
    }
  }
  __syncthreads();

  // layer 2: wave w -> rows [w*32, w*32+32)
  f32x4 acc2[2][7] = {};
#pragma unroll
  for (int ks = 0; ks < 4; ++ks) {
    bf16x8 a2_0 = *(const bf16x8*)((const unsigned short*)h_tile + (w * 32 + lm) * 136 + ks * 32 + lq * 8);
    bf16x8 a2_1 = *(const bf16x8*)((const unsigned short*)h_tile + (w * 32 + 16 + lm) * 136 + ks * 32 + lq * 8);
#pragma unroll
    for (int nf = 0; nf < 7; ++nf) {
      bf16x8 b2f = *(const bf16x8*)((const unsigned short*)W2T + (nf * 16 + lm) * NH + ks * 32 + lq * 8);
      acc2[0][nf] = __builtin_amdgcn_mfma_f32_16x16x32_bf16(a2_0, b2f, acc2[0][nf], 0, 0, 0);
      acc2[1][nf] = __builtin_amdgcn_mfma_f32_16x16x32_bf16(a2_1, b2f, acc2[1][nf], 0, 0, 0);
    }
  }

#pragma unroll
  for (int mf2 = 0; mf2 < 2; ++mf2) {
    int mbase = w * 32 + mf2 * 16 + lq * 4;
#pragma unroll
    for (int nf = 0; nf < 7; ++nf) {
      float ssum = 0.f;
#pragma unroll
      for (int rg = 0; rg < 4; ++rg) {
        int m = mbase + rg;
        ssum += (m < NR) ? acc2[mf2][nf][rg] : 0.f;
      }
      ssum += __shfl_xor(ssum, 16, 64);
      ssum += __shfl_xor(ssum, 32, 64);
      if (lq == 0) partial[(w * 2 + mf2) * 112 + nf * 16 + lm] = ssum;
    }
  }
  __syncthreads();

  if (tid < NC) {
    float fsum = 0.f;
#pragma unroll
    for (int p = 0; p < 8; ++p) fsum += partial[p * 112 + tid];
    out[b * NC + tid] = fsum * (1.f / NR) + b2[tid];
  }
}

extern "C" void kernel_launch(void* const* d_in, const int* in_sizes, int n_in,
                              void* d_out, int out_size, void* d_ws, size_t ws_size,
                              hipStream_t stream) {
  (void)in_sizes; (void)n_in; (void)out_size; (void)ws_size;
  const int* x     = (const int*)d_in[0];
  const int* noise = (const int*)d_in[1];
  const float* W1  = (const float*)d_in[2];
  const float* b1  = (const float*)d_in[3];
  const float* W2  = (const float*)d_in[4];
  const float* b2  = (const float*)d_in[5];
  float* out = (float*)d_out;

  __hip_bfloat16* W1T = (__hip_bfloat16*)d_ws;
  __hip_bfloat16* W2T = (__hip_bfloat16*)((char*)d_ws + (size_t)NH * DP * 2);

  prep_w1t<<<DP / KSTEP, 256, 0, stream>>>(W1, W1T);
  prep_w2t<<<(CP * NH + 255) / 256, 256, 0, stream>>>(W2, W2T);
  fused_main<<<NB, 256, 0, stream>>>(x, noise, W1T, b1, W2T, b2, out);
}